// Round 15
// baseline (5476.072 us; speedup 1.0000x reference)
//
#include <hip/hip_runtime.h>

#define N_TOTAL 150000   // N_USERS + M_ITEMS
#define DIM 64
#define RPB 293          // rows per bucket
#define NBUCK 512        // buckets == co-resident block slots (2/CU x 256)
#define MAGIC 14658592u  // ceil(2^32/293): __umulhi(r,MAGIC) == r/293 for r<2^24
#define CAP 10368        // bucket capacity (mean 9375 + ~10 sigma)
#define CHUNK 8192       // edges per binning block (512 thr x 16)
#define ASTRIDE 65       // acc row stride (floats): 65%32==1 -> bank spread

typedef float v2f __attribute__((ext_vector_type(2)));

__global__ void fill_bcur_kernel(int* __restrict__ bcur) {
    int t = blockIdx.x * 256 + threadIdx.x;
    if (t < NBUCK) bcur[t] = t * CAP;
}

// Phase B: LDS-sorted multisplit into 512 row-range buckets; coalesced stream-out.
// Records: bcs[dst] = col(18b)<<14 | val14 ; brl[dst] = rowLocal (u16).
__global__ void bin_kernel(const int* __restrict__ idx, const float* __restrict__ val,
                           int* __restrict__ bcur, unsigned* __restrict__ bcs,
                           unsigned short* __restrict__ brl, int nnz) {
    __shared__ unsigned scs[CHUNK];       // 32 KB
    __shared__ unsigned srow[CHUNK];      // 32 KB
    __shared__ int lcnt[NBUCK];
    __shared__ int lstart[NBUCK + 1];
    __shared__ int gbase[NBUCK];
    int t = threadIdx.x;
    int base = blockIdx.x * CHUNK;
    int nEdges = min(CHUNK, nnz - base);
    lcnt[t] = 0;
    __syncthreads();
    unsigned mycs[16];
    int myrow[16], myb[16];
    #pragma unroll
    for (int i = 0; i < 16; ++i) {
        int e = base + t + i * 512;
        if (e < nnz) {
            int r = idx[e];
            int b = (int)__umulhi((unsigned)r, MAGIC);
            myb[i] = b;
            myrow[i] = r;
            unsigned v14 = (__float_as_uint(val[e]) + 0x20000u) >> 18;
            mycs[i] = ((unsigned)idx[nnz + e] << 14) | v14;
            atomicAdd(&lcnt[b], 1);
        } else {
            myb[i] = -1;
        }
    }
    __syncthreads();
    int c = lcnt[t];
    lstart[t] = c;
    __syncthreads();
    for (int off = 1; off < 512; off <<= 1) {
        int x = (t >= off) ? lstart[t - off] : 0;
        __syncthreads();
        lstart[t] += x;
        __syncthreads();
    }
    int incl = lstart[t];
    __syncthreads();
    lstart[t] = incl - c;                  // exclusive
    if (t == 511) lstart[512] = incl;      // total
    gbase[t] = c ? atomicAdd(&bcur[t], c) : 0;
    lcnt[t] = 0;                           // reuse as placement cursor
    __syncthreads();
    #pragma unroll
    for (int i = 0; i < 16; ++i) {
        int b = myb[i];
        if (b >= 0) {
            int o = atomicAdd(&lcnt[b], 1);
            int p = lstart[b] + o;
            scs[p] = mycs[i];
            srow[p] = (unsigned)myrow[i];
        }
    }
    __syncthreads();
    for (int p = t; p < nEdges; p += 512) {
        int r = (int)srow[p];
        int b = (int)__umulhi((unsigned)r, MAGIC);
        int dst = gbase[b] + (p - lstart[b]);
        if (dst < (b + 1) * CAP) {         // overflow guard (never hit)
            bcs[dst] = scs[p];
            brl[dst] = (unsigned short)(r - b * RPB);
        }
    }
}

// Phase C (row variant, reg path): per-bucket ROW-grouped CSR -> cs2 + rlo/rhi.
__global__ void scatterc_row_kernel(const unsigned* __restrict__ bcs,
                                    const unsigned short* __restrict__ brl,
                                    const int* __restrict__ bcur,
                                    int* __restrict__ rlo, int* __restrict__ rhi,
                                    unsigned* __restrict__ cs2) {
    __shared__ int hist[RPB];
    __shared__ int ssc[256];
    int b = blockIdx.x, t = threadIdx.x;
    int s = b * CAP, e = min(bcur[b], s + CAP);
    for (int i = t; i < RPB; i += 256) hist[i] = 0;
    __syncthreads();
    for (int k = s + t; k < e; k += 256)
        atomicAdd(&hist[brl[k]], 1);
    __syncthreads();
    int i0 = 2 * t;
    int c0 = (i0 < RPB) ? hist[i0] : 0;
    int c1 = (i0 + 1 < RPB) ? hist[i0 + 1] : 0;
    int s2 = c0 + c1;
    ssc[t] = s2;
    __syncthreads();
    for (int off = 1; off < 256; off <<= 1) {
        int x = (t >= off) ? ssc[t - off] : 0;
        __syncthreads();
        ssc[t] += x;
        __syncthreads();
    }
    int excl = ssc[t] - s2;
    __syncthreads();
    int base0 = s + excl, base1 = s + excl + c0;
    if (i0 < RPB) {
        int row = b * RPB + i0;
        if (row < N_TOTAL) { rlo[row] = base0; rhi[row] = base0 + c0; }
        hist[i0] = base0;
    }
    if (i0 + 1 < RPB) {
        int row = b * RPB + i0 + 1;
        if (row < N_TOTAL) { rlo[row] = base1; rhi[row] = base1 + c1; }
        hist[i0 + 1] = base1;
    }
    __syncthreads();
    for (int k = s + t; k < e; k += 256) {
        int rl_ = brl[k];
        int o = atomicAdd(&hist[rl_], 1);
        cs2[o] = bcs[k];
    }
}

// Phase C (col variant, sweep path): per-bucket COLUMN sort (512 col-bins) ->
// cs2 + rl2. Col-sorted order makes the 512 co-resident sweep blocks scan the
// gather table in a synchronized band (proven 104MB FETCH, round 10).
__global__ void scatterc_col_kernel(const unsigned* __restrict__ bcs,
                                    const unsigned short* __restrict__ brl,
                                    const int* __restrict__ bcur,
                                    unsigned* __restrict__ cs2,
                                    unsigned short* __restrict__ rl2) {
    __shared__ int hist[NBUCK];
    __shared__ int ssc[256];
    int b = blockIdx.x, t = threadIdx.x;
    int s = b * CAP, e = min(bcur[b], s + CAP);
    hist[t] = 0; hist[t + 256] = 0;
    __syncthreads();
    for (int k = s + t; k < e; k += 256)
        atomicAdd(&hist[__umulhi(bcs[k] >> 14, MAGIC)], 1);
    __syncthreads();
    int i0 = 2 * t;
    int c0 = hist[i0], c1 = hist[i0 + 1];
    int s2 = c0 + c1;
    ssc[t] = s2;
    __syncthreads();
    for (int off = 1; off < 256; off <<= 1) {
        int x = (t >= off) ? ssc[t - off] : 0;
        __syncthreads();
        ssc[t] += x;
        __syncthreads();
    }
    int excl = ssc[t] - s2;
    __syncthreads();
    hist[i0] = s + excl;
    hist[i0 + 1] = s + excl + c0;
    __syncthreads();
    for (int k = s + t; k < e; k += 256) {
        unsigned wv = bcs[k];
        int cb = (int)__umulhi(wv >> 14, MAGIC);
        int o = atomicAdd(&hist[cb], 1);
        cs2[o] = wv;
        rl2[o] = brl[k];
    }
}

// f32 -> fp8(e4m3, x64) DIM-PERMUTED table: word w of a row packs dims
// {w, w+16, w+32, w+48} in bytes 0..3. (reg-spmm is layout-agnostic.)
__global__ void conv_fp8_kernel(const float* __restrict__ x, unsigned* __restrict__ y,
                                int nwords) {
    int i = blockIdx.x * blockDim.x + threadIdx.x;
    if (i >= nwords) return;
    int row = i >> 4, w = i & 15;
    const float* xr = x + ((size_t)row << 6) + w;
    int p = __builtin_amdgcn_cvt_pk_fp8_f32(xr[0] * 64.f, xr[16] * 64.f, 0, false);
    p = __builtin_amdgcn_cvt_pk_fp8_f32(xr[32] * 64.f, xr[48] * 64.f, p, true);
    y[i] = (unsigned)p;
}

// ---- reg-accumulator pull SpMM (round-13 proven, 75us). Layout-agnostic. ----
__global__ void spmm_reg_kernel(const int* __restrict__ rlo, const int* __restrict__ rhi,
                                const unsigned* __restrict__ cs, const uint2* __restrict__ x2,
                                uint2* __restrict__ y2, int nrows) {
    int gid = blockIdx.x * blockDim.x + threadIdx.x;
    int row = gid >> 6;
    int lane = gid & 63;
    if (row >= nrows) return;
    int s = rlo[row], e = rhi[row];
    int q = lane >> 3, sub = lane & 7;
    float ac[8], bc[8];
    #pragma unroll
    for (int d = 0; d < 8; ++d) { ac[d] = 0.f; bc[d] = 0.f; }
    int k = s + q;
    for (; k + 8 < e; k += 16) {
        unsigned ed0 = cs[k], ed1 = cs[k + 8];
        uint2 g0 = x2[((size_t)(ed0 >> 14) << 3) + sub];
        uint2 g1 = x2[((size_t)(ed1 >> 14) << 3) + sub];
        float v0 = __uint_as_float((ed0 & 0x3FFFu) << 18);
        float v1 = __uint_as_float((ed1 & 0x3FFFu) << 18);
        v2f l0 = __builtin_amdgcn_cvt_pk_f32_fp8((int)g0.x, false);
        v2f h0 = __builtin_amdgcn_cvt_pk_f32_fp8((int)g0.x, true);
        v2f l1 = __builtin_amdgcn_cvt_pk_f32_fp8((int)g0.y, false);
        v2f h1 = __builtin_amdgcn_cvt_pk_f32_fp8((int)g0.y, true);
        ac[0] += v0 * l0.x; ac[1] += v0 * l0.y; ac[2] += v0 * h0.x; ac[3] += v0 * h0.y;
        ac[4] += v0 * l1.x; ac[5] += v0 * l1.y; ac[6] += v0 * h1.x; ac[7] += v0 * h1.y;
        v2f l2 = __builtin_amdgcn_cvt_pk_f32_fp8((int)g1.x, false);
        v2f h2 = __builtin_amdgcn_cvt_pk_f32_fp8((int)g1.x, true);
        v2f l3 = __builtin_amdgcn_cvt_pk_f32_fp8((int)g1.y, false);
        v2f h3 = __builtin_amdgcn_cvt_pk_f32_fp8((int)g1.y, true);
        bc[0] += v1 * l2.x; bc[1] += v1 * l2.y; bc[2] += v1 * h2.x; bc[3] += v1 * h2.y;
        bc[4] += v1 * l3.x; bc[5] += v1 * l3.y; bc[6] += v1 * h3.x; bc[7] += v1 * h3.y;
    }
    for (; k < e; k += 8) {
        unsigned ed = cs[k];
        uint2 g = x2[((size_t)(ed >> 14) << 3) + sub];
        float vv = __uint_as_float((ed & 0x3FFFu) << 18);
        v2f l0 = __builtin_amdgcn_cvt_pk_f32_fp8((int)g.x, false);
        v2f h0 = __builtin_amdgcn_cvt_pk_f32_fp8((int)g.x, true);
        v2f l1 = __builtin_amdgcn_cvt_pk_f32_fp8((int)g.y, false);
        v2f h1 = __builtin_amdgcn_cvt_pk_f32_fp8((int)g.y, true);
        ac[0] += vv * l0.x; ac[1] += vv * l0.y; ac[2] += vv * h0.x; ac[3] += vv * h0.y;
        ac[4] += vv * l1.x; ac[5] += vv * l1.y; ac[6] += vv * h1.x; ac[7] += vv * h1.y;
    }
    #pragma unroll
    for (int d = 0; d < 8; ++d) {
        float a = ac[d] + bc[d];
        a += __shfl_xor(a, 8);
        a += __shfl_xor(a, 16);
        a += __shfl_xor(a, 32);
        ac[d] = a;
    }
    if (q == 0) {
        int p0 = __builtin_amdgcn_cvt_pk_fp8_f32(ac[0], ac[1], 0, false);
        p0 = __builtin_amdgcn_cvt_pk_fp8_f32(ac[2], ac[3], p0, true);
        int p1 = __builtin_amdgcn_cvt_pk_fp8_f32(ac[4], ac[5], 0, false);
        p1 = __builtin_amdgcn_cvt_pk_fp8_f32(ac[6], ac[7], p1, true);
        uint2 o;
        o.x = (unsigned)p0;
        o.y = (unsigned)p1;
        y2[((size_t)row << 3) + sub] = o;
    }
}

// ---- bucket-resident SWEEP SpMM: col-sorted edges, LDS f32 accumulation via
// raw ds_add_f32 (inline asm -- bypasses the CAS lowering that killed r10/r11).
// Permuted table: lane sub gathers word sub (dims {sub,sub+16,sub+32,sub+48}),
// ds_adds land on 16 consecutive banks per group. 2-deep pipelined. ----
__global__ __launch_bounds__(256)
void spmm_sweep_kernel(const unsigned short* __restrict__ rl2,
                       const unsigned* __restrict__ cs2,
                       const int* __restrict__ bcur,
                       const unsigned* __restrict__ x,
                       unsigned* __restrict__ y) {
    __shared__ float acc[RPB * ASTRIDE];   // 76,180 B -> 2 blocks/CU
    int b = blockIdx.x, t = threadIdx.x;
    int s = b * CAP, e = min(bcur[b], s + CAP);
    for (int i = t; i < RPB * ASTRIDE; i += 256) acc[i] = 0.f;
    __syncthreads();
    int g = t >> 4, sub = t & 15;
    int k = s + g;
    unsigned ed = 0, gx = 0;
    int r = 0;
    bool have = (k < e);
    if (have) { ed = cs2[k]; r = rl2[k]; gx = x[((size_t)(ed >> 14) << 4) + sub]; }
    while (have) {
        int kn = k + 16;
        unsigned edn = 0, gxn = 0;
        int rn = 0;
        bool haven = (kn < e);
        if (haven) { edn = cs2[kn]; rn = rl2[kn]; gxn = x[((size_t)(edn >> 14) << 4) + sub]; }
        float vv = __uint_as_float((ed & 0x3FFFu) << 18);
        v2f lo = __builtin_amdgcn_cvt_pk_f32_fp8((int)gx, false);
        v2f hi = __builtin_amdgcn_cvt_pk_f32_fp8((int)gx, true);
        float p0 = vv * lo.x, p1 = vv * lo.y, p2 = vv * hi.x, p3 = vv * hi.y;
        // LDS aperture is 4GB-aligned: low 32 bits of the generic pointer ==
        // LDS byte offset. +64B = +16 floats.
        unsigned off = (unsigned)(unsigned long long)(&acc[r * ASTRIDE + sub]);
        asm volatile("ds_add_f32 %0, %1" :: "v"(off), "v"(p0));
        asm volatile("ds_add_f32 %0, %1 offset:64" :: "v"(off), "v"(p1));
        asm volatile("ds_add_f32 %0, %1 offset:128" :: "v"(off), "v"(p2));
        asm volatile("ds_add_f32 %0, %1 offset:192" :: "v"(off), "v"(p3));
        k = kn; ed = edn; r = rn; gx = gxn; have = haven;
    }
    asm volatile("" ::: "memory");
    __syncthreads();
    int wd = t & 15;
    for (int rr = t >> 4; rr < RPB; rr += 16) {
        int row = b * RPB + rr;
        if (row >= N_TOTAL) break;
        float a0 = acc[rr * ASTRIDE + wd];
        float a1 = acc[rr * ASTRIDE + wd + 16];
        float a2 = acc[rr * ASTRIDE + wd + 32];
        float a3 = acc[rr * ASTRIDE + wd + 48];
        int p = __builtin_amdgcn_cvt_pk_fp8_f32(a0, a1, 0, false);
        p = __builtin_amdgcn_cvt_pk_fp8_f32(a2, a3, p, true);
        y[((size_t)row << 4) + wd] = (unsigned)p;   // permuted word wd
    }
}

// decode permuted word i of 3 stacked tables; component c = dim w+16c
__device__ inline float4 dec_sum3(const unsigned* __restrict__ T, int i, int nwords) {
    unsigned a = T[i], b = T[i + nwords], c = T[i + 2 * nwords];
    v2f alo = __builtin_amdgcn_cvt_pk_f32_fp8((int)a, false);
    v2f ahi = __builtin_amdgcn_cvt_pk_f32_fp8((int)a, true);
    v2f blo = __builtin_amdgcn_cvt_pk_f32_fp8((int)b, false);
    v2f bhi = __builtin_amdgcn_cvt_pk_f32_fp8((int)b, true);
    v2f clo = __builtin_amdgcn_cvt_pk_f32_fp8((int)c, false);
    v2f chi = __builtin_amdgcn_cvt_pk_f32_fp8((int)c, true);
    float4 r;
    r.x = alo.x + blo.x + clo.x;
    r.y = alo.y + blo.y + clo.y;
    r.z = ahi.x + bhi.x + chi.x;
    r.w = ahi.y + bhi.y + chi.y;
    return r;
}

// ---- fused combine (permuted): out = sum_f (w[f]/4)*(emb_f + (A+B+C)/64) ----
__global__ void combine3_kernel(const float* __restrict__ e0, const float* __restrict__ e1,
                                const float* __restrict__ e2, const unsigned* __restrict__ t0,
                                const unsigned* __restrict__ t1, const unsigned* __restrict__ t2,
                                const float* __restrict__ w, float* __restrict__ out,
                                int nwords) {
    int i = blockIdx.x * blockDim.x + threadIdx.x;
    if (i >= nwords) return;
    const float kInv = 1.f / 64.f;
    float c0 = w[0] * 0.25f, c1 = w[1] * 0.25f, c2 = w[2] * 0.25f;
    int r = i >> 4, wd = i & 15;
    size_t base = ((size_t)r << 6) + wd;
    float4 s0 = dec_sum3(t0, i, nwords);
    float4 s1 = dec_sum3(t1, i, nwords);
    float4 s2 = dec_sum3(t2, i, nwords);
    out[base]      = c0 * (e0[base]      + kInv * s0.x) + c1 * (e1[base]      + kInv * s1.x)
                   + c2 * (e2[base]      + kInv * s2.x);
    out[base + 16] = c0 * (e0[base + 16] + kInv * s0.y) + c1 * (e1[base + 16] + kInv * s1.y)
                   + c2 * (e2[base + 16] + kInv * s2.y);
    out[base + 32] = c0 * (e0[base + 32] + kInv * s0.z) + c1 * (e1[base + 32] + kInv * s1.z)
                   + c2 * (e2[base + 32] + kInv * s2.z);
    out[base + 48] = c0 * (e0[base + 48] + kInv * s0.w) + c1 * (e1[base + 48] + kInv * s1.w)
                   + c2 * (e2[base + 48] + kInv * s2.w);
}

// ---- per-factor combine fallback (permuted) ----
template <bool FIRST>
__global__ void combine_kernel(const float* __restrict__ emb, const unsigned* __restrict__ T,
                               const float* __restrict__ w, int f, float* __restrict__ out,
                               int nwords) {
    int i = blockIdx.x * blockDim.x + threadIdx.x;
    if (i >= nwords) return;
    float c = w[f] * 0.25f;
    const float kInv = 1.f / 64.f;
    int r = i >> 4, wd = i & 15;
    size_t base = ((size_t)r << 6) + wd;
    float4 s = dec_sum3(T, i, nwords);
    float v0 = c * (emb[base] + kInv * s.x);
    float v1 = c * (emb[base + 16] + kInv * s.y);
    float v2 = c * (emb[base + 32] + kInv * s.z);
    float v3 = c * (emb[base + 48] + kInv * s.w);
    if (FIRST) {
        out[base] = v0; out[base + 16] = v1; out[base + 32] = v2; out[base + 48] = v3;
    } else {
        out[base] += v0; out[base + 16] += v1; out[base + 32] += v2; out[base + 48] += v3;
    }
}

extern "C" void kernel_launch(void* const* d_in, const int* in_sizes, int n_in,
                              void* d_out, int out_size, void* d_ws, size_t ws_size,
                              hipStream_t stream) {
    const float* emb[3]  = {(const float*)d_in[0], (const float*)d_in[1], (const float*)d_in[2]};
    const int*   gidx[3] = {(const int*)d_in[3],   (const int*)d_in[5],   (const int*)d_in[7]};
    const float* gval[3] = {(const float*)d_in[4], (const float*)d_in[6], (const float*)d_in[8]};
    const float* w = (const float*)d_in[9];
    float* out = (float*)d_out;

    const int nnz = in_sizes[4];
    const size_t bufElems = (size_t)N_TOTAL * DIM;       // 9.6M
    const size_t fp8Bytes = bufElems;                    // 9.6 MB per table
    const size_t capElems = (size_t)NBUCK * CAP;         // 5.31M entries

    // ws layout:
    //   [0, 21.2MB)       bcs (u32)      -- emb8 (9.6MB) aliases after scatterc
    //   [21.2, 31.9MB)    brl (u16)
    //   [31.9, 53.1MB)    cs2 (u32)      -- col-sorted (f0) or row-grouped (f1/2)
    //   [53.1, 63.7MB)    rl2 (u16)      -- sweep path only
    //   [63.7MB+...]      rlo, rhi, bcur
    //   then              fp8 layer tables (9 fused / 3 fallback)
    char* base = (char*)d_ws;
    unsigned*       bcs  = (unsigned*)base;
    unsigned*       emb8 = (unsigned*)base;                  // alias
    unsigned short* brl  = (unsigned short*)(base + capElems * 4);
    unsigned*       cs2  = (unsigned*)(base + capElems * 6);
    unsigned short* rl2  = (unsigned short*)(base + capElems * 10);
    int*            rlo  = (int*)(base + capElems * 12);
    int*            rhi  = rlo + N_TOTAL;
    int*            bcur = rhi + N_TOTAL;
    char*           tab  = base + capElems * 12 + (size_t)2 * N_TOTAL * 4 + 4096;
    const size_t needFused = (size_t)(tab - base) + (size_t)9 * fp8Bytes;   // ~151 MB
    const bool fused = ws_size >= needFused;

    const int nwords = (int)(bufElems / 4);               // N_TOTAL*16
    dim3 cvtGrid((nwords + 255) / 256);
    dim3 cmbGrid((nwords + 255) / 256);
    dim3 chunkGrid((nnz + CHUNK - 1) / CHUNK);            // 586
    dim3 rowGrid((unsigned)(((size_t)N_TOTAL * 64 + 255) / 256));

    for (int f = 0; f < 3; ++f) {
        unsigned* A8 = (unsigned*)(tab + (size_t)(fused ? 3 * f + 0 : 0) * fp8Bytes);
        unsigned* B8 = (unsigned*)(tab + (size_t)(fused ? 3 * f + 1 : 1) * fp8Bytes);
        unsigned* C8 = (unsigned*)(tab + (size_t)(fused ? 3 * f + 2 : 2) * fp8Bytes);

        fill_bcur_kernel<<<2, 256, 0, stream>>>(bcur);
        bin_kernel<<<chunkGrid, 512, 0, stream>>>(gidx[f], gval[f], bcur, bcs, brl, nnz);

        if (f == 0) {
            // SWEEP path: col-sorted edges, LDS-resident accumulators.
            scatterc_col_kernel<<<NBUCK, 256, 0, stream>>>(bcs, brl, bcur, cs2, rl2);
            conv_fp8_kernel<<<cvtGrid, 256, 0, stream>>>(emb[f], emb8, nwords);
            spmm_sweep_kernel<<<NBUCK, 256, 0, stream>>>(rl2, cs2, bcur, emb8, A8);
            spmm_sweep_kernel<<<NBUCK, 256, 0, stream>>>(rl2, cs2, bcur, A8, B8);
            spmm_sweep_kernel<<<NBUCK, 256, 0, stream>>>(rl2, cs2, bcur, B8, C8);
        } else {
            // REG path (round-13 proven).
            scatterc_row_kernel<<<NBUCK, 256, 0, stream>>>(bcs, brl, bcur, rlo, rhi, cs2);
            conv_fp8_kernel<<<cvtGrid, 256, 0, stream>>>(emb[f], emb8, nwords);
            spmm_reg_kernel<<<rowGrid, 256, 0, stream>>>(rlo, rhi, cs2, (const uint2*)emb8,
                                                         (uint2*)A8, N_TOTAL);
            spmm_reg_kernel<<<rowGrid, 256, 0, stream>>>(rlo, rhi, cs2, (const uint2*)A8,
                                                         (uint2*)B8, N_TOTAL);
            spmm_reg_kernel<<<rowGrid, 256, 0, stream>>>(rlo, rhi, cs2, (const uint2*)B8,
                                                         (uint2*)C8, N_TOTAL);
        }

        if (!fused) {
            if (f == 0)
                combine_kernel<true><<<cmbGrid, 256, 0, stream>>>(emb[f], A8, w, f, out, nwords);
            else
                combine_kernel<false><<<cmbGrid, 256, 0, stream>>>(emb[f], A8, w, f, out, nwords);
        }
    }

    if (fused) {
        const unsigned* t0 = (const unsigned*)(tab + (size_t)0 * fp8Bytes);
        const unsigned* t1 = (const unsigned*)(tab + (size_t)3 * fp8Bytes);
        const unsigned* t2 = (const unsigned*)(tab + (size_t)6 * fp8Bytes);
        combine3_kernel<<<cmbGrid, 256, 0, stream>>>(emb[0], emb[1], emb[2], t0, t1, t2,
                                                     w, out, nwords);
    }
}

// Round 16
// 1072.805 us; speedup vs baseline: 5.1044x; 5.1044x over previous
//
#include <hip/hip_runtime.h>

#define N_TOTAL 150000   // N_USERS + M_ITEMS
#define DIM 64
#define RPB 293          // rows per bucket
#define NBUCK 512        // buckets
#define MAGIC 14658592u  // ceil(2^32/293): __umulhi(r,MAGIC) == r/293 for r<2^24
#define CAP 10368        // fixed bucket capacity (mean 9375 + ~10 sigma)
#define CHUNK 4096       // edges per binning block (256 thr x 16) -> 39KB LDS, 4 blk/CU

typedef float v2f __attribute__((ext_vector_type(2)));

__global__ void fill_bcur_kernel(int* __restrict__ bcur) {
    int t = blockIdx.x * 256 + threadIdx.x;
    if (t < NBUCK) bcur[t] = t * CAP;
}

// Phase B: LDS-sorted multisplit into 512 row-range buckets; coalesced stream-out.
// Records: bcs[dst] = col(18b)<<14 | val14 ; brl[dst] = rowLocal (u16).
// 256 thr / 4096 edges -> 39KB LDS -> 4 blocks/CU (vs 2 at 512thr/8192).
__global__ void bin_kernel(const int* __restrict__ idx, const float* __restrict__ val,
                           int* __restrict__ bcur, unsigned* __restrict__ bcs,
                           unsigned short* __restrict__ brl, int nnz) {
    __shared__ unsigned scs[CHUNK];       // 16 KB
    __shared__ unsigned srow[CHUNK];      // 16 KB
    __shared__ int lcnt[NBUCK];
    __shared__ int lstart[NBUCK + 1];
    __shared__ int gbase[NBUCK];
    __shared__ int ssc[256];
    int t = threadIdx.x;
    int base = blockIdx.x * CHUNK;
    int nEdges = min(CHUNK, nnz - base);
    lcnt[t] = 0; lcnt[t + 256] = 0;
    __syncthreads();
    unsigned mycs[16];
    int myrow[16], myb[16];
    #pragma unroll
    for (int i = 0; i < 16; ++i) {
        int e = base + t + i * 256;
        if (e < nnz) {
            int r = idx[e];
            int b = (int)__umulhi((unsigned)r, MAGIC);
            myb[i] = b;
            myrow[i] = r;
            unsigned v14 = (__float_as_uint(val[e]) + 0x20000u) >> 18;
            mycs[i] = ((unsigned)idx[nnz + e] << 14) | v14;
            atomicAdd(&lcnt[b], 1);
        } else {
            myb[i] = -1;
        }
    }
    __syncthreads();
    // exclusive scan of lcnt[0..511], 2 elems/thread
    int i0 = 2 * t;
    int c0 = lcnt[i0], c1 = lcnt[i0 + 1];
    int s2 = c0 + c1;
    ssc[t] = s2;
    __syncthreads();
    for (int off = 1; off < 256; off <<= 1) {
        int x = (t >= off) ? ssc[t - off] : 0;
        __syncthreads();
        ssc[t] += x;
        __syncthreads();
    }
    int incl = ssc[t];
    int excl = incl - s2;
    lstart[i0] = excl;
    lstart[i0 + 1] = excl + c0;
    if (t == 255) lstart[NBUCK] = incl;
    gbase[i0]     = c0 ? atomicAdd(&bcur[i0], c0) : 0;
    gbase[i0 + 1] = c1 ? atomicAdd(&bcur[i0 + 1], c1) : 0;
    lcnt[i0] = 0; lcnt[i0 + 1] = 0;    // reuse as placement cursors
    __syncthreads();
    #pragma unroll
    for (int i = 0; i < 16; ++i) {
        int b = myb[i];
        if (b >= 0) {
            int o = atomicAdd(&lcnt[b], 1);
            int p = lstart[b] + o;
            scs[p] = mycs[i];
            srow[p] = (unsigned)myrow[i];
        }
    }
    __syncthreads();
    for (int p = t; p < nEdges; p += 256) {
        int r = (int)srow[p];
        int b = (int)__umulhi((unsigned)r, MAGIC);
        int dst = gbase[b] + (p - lstart[b]);
        if (dst < (b + 1) * CAP) {         // overflow guard (never hit)
            bcs[dst] = scs[p];
            brl[dst] = (unsigned short)(r - b * RPB);
        }
    }
}

// ---- device bodies for the merged scatterc+conv+combine dispatch ----

// Per-bucket ROW-grouped CSR placement; resets bcur[b] for the next factor.
__device__ void scatterc_body(int b, const unsigned* __restrict__ bcs,
                              const unsigned short* __restrict__ brl,
                              int* __restrict__ bcur,
                              int* __restrict__ rlo, int* __restrict__ rhi,
                              unsigned* __restrict__ cs2) {
    __shared__ int hist[RPB];
    __shared__ int ssc[256];
    int t = threadIdx.x;
    int s = b * CAP, e = min(bcur[b], s + CAP);
    for (int i = t; i < RPB; i += 256) hist[i] = 0;
    __syncthreads();
    for (int k = s + t; k < e; k += 256)
        atomicAdd(&hist[brl[k]], 1);
    __syncthreads();
    int i0 = 2 * t;
    int c0 = (i0 < RPB) ? hist[i0] : 0;
    int c1 = (i0 + 1 < RPB) ? hist[i0 + 1] : 0;
    int s2 = c0 + c1;
    ssc[t] = s2;
    __syncthreads();
    for (int off = 1; off < 256; off <<= 1) {
        int x = (t >= off) ? ssc[t - off] : 0;
        __syncthreads();
        ssc[t] += x;
        __syncthreads();
    }
    int excl = ssc[t] - s2;
    __syncthreads();
    int base0 = s + excl, base1 = s + excl + c0;
    if (i0 < RPB) {
        int row = b * RPB + i0;
        if (row < N_TOTAL) { rlo[row] = base0; rhi[row] = base0 + c0; }
        hist[i0] = base0;
    }
    if (i0 + 1 < RPB) {
        int row = b * RPB + i0 + 1;
        if (row < N_TOTAL) { rlo[row] = base1; rhi[row] = base1 + c1; }
        hist[i0 + 1] = base1;
    }
    __syncthreads();
    for (int k = s + t; k < e; k += 256) {
        int rl_ = brl[k];
        int o = atomicAdd(&hist[rl_], 1);
        cs2[o] = bcs[k];
    }
    __syncthreads();
    if (t == 0) bcur[b] = s;              // reset cursor for next factor's bin
}

// f32 -> fp8(e4m3, x64) DIM-PERMUTED table: word w of a row packs dims
// {w, w+16, w+32, w+48}.
__device__ void conv_body(int i, const float* __restrict__ x, unsigned* __restrict__ y,
                          int nwords) {
    if (i >= nwords) return;
    int row = i >> 4, w_ = i & 15;
    const float* xr = x + ((size_t)row << 6) + w_;
    int p = __builtin_amdgcn_cvt_pk_fp8_f32(xr[0] * 64.f, xr[16] * 64.f, 0, false);
    p = __builtin_amdgcn_cvt_pk_fp8_f32(xr[32] * 64.f, xr[48] * 64.f, p, true);
    y[i] = (unsigned)p;
}

// decode permuted word i of 3 stacked tables (A at 0, B at nwords, C at 2*nwords)
__device__ inline float4 dec_sum3(const unsigned* __restrict__ T, int i, int nwords) {
    unsigned a = T[i], b = T[i + nwords], c = T[i + 2 * nwords];
    v2f alo = __builtin_amdgcn_cvt_pk_f32_fp8((int)a, false);
    v2f ahi = __builtin_amdgcn_cvt_pk_f32_fp8((int)a, true);
    v2f blo = __builtin_amdgcn_cvt_pk_f32_fp8((int)b, false);
    v2f bhi = __builtin_amdgcn_cvt_pk_f32_fp8((int)b, true);
    v2f clo = __builtin_amdgcn_cvt_pk_f32_fp8((int)c, false);
    v2f chi = __builtin_amdgcn_cvt_pk_f32_fp8((int)c, true);
    float4 r;
    r.x = alo.x + blo.x + clo.x;
    r.y = alo.y + blo.y + clo.y;
    r.z = ahi.x + bhi.x + chi.x;
    r.w = ahi.y + bhi.y + chi.y;
    return r;
}

// out (+)= c * (emb + (A+B+C)/64), permuted-table decode
__device__ void combine_body(int i, const float* __restrict__ emb,
                             const unsigned* __restrict__ T, float c,
                             float* __restrict__ out, int nwords, bool first) {
    if (i >= nwords) return;
    const float kInv = 1.f / 64.f;
    int r = i >> 4, wd = i & 15;
    size_t base = ((size_t)r << 6) + wd;
    float4 s = dec_sum3(T, i, nwords);
    float v0 = c * (emb[base] + kInv * s.x);
    float v1 = c * (emb[base + 16] + kInv * s.y);
    float v2 = c * (emb[base + 32] + kInv * s.z);
    float v3 = c * (emb[base + 48] + kInv * s.w);
    if (first) {
        out[base] = v0; out[base + 16] = v1; out[base + 32] = v2; out[base + 48] = v3;
    } else {
        out[base] += v0; out[base + 16] += v1; out[base + 32] += v2; out[base + 48] += v3;
    }
}

// Merged dispatch: blocks [0,NBUCK) scatterc(f); [NBUCK,NBUCK+nCvt) conv(f);
// rest (if hasCmb) combine(f-1). All independent buffers.
__global__ void scv_kernel(const unsigned* __restrict__ bcs,
                           const unsigned short* __restrict__ brl,
                           int* __restrict__ bcur, int* __restrict__ rlo,
                           int* __restrict__ rhi, unsigned* __restrict__ cs2,
                           const float* __restrict__ embf, unsigned* __restrict__ emb8,
                           const float* __restrict__ embp, const unsigned* __restrict__ Tp,
                           const float* __restrict__ w, int fprev, float* __restrict__ out,
                           int nwords, int nCvt) {
    int b = blockIdx.x;
    if (b < NBUCK) {
        scatterc_body(b, bcs, brl, bcur, rlo, rhi, cs2);
        return;
    }
    b -= NBUCK;
    if (b < nCvt) {
        conv_body(b * 256 + (int)threadIdx.x, embf, emb8, nwords);
        return;
    }
    b -= nCvt;
    combine_body(b * 256 + (int)threadIdx.x, embp, Tp, w[fprev] * 0.25f, out, nwords,
                 fprev == 0);
}

// standalone combine (last factor)
__global__ void combine_kernel(const float* __restrict__ emb, const unsigned* __restrict__ T,
                               const float* __restrict__ w, int f, float* __restrict__ out,
                               int nwords) {
    combine_body(blockIdx.x * 256 + (int)threadIdx.x, emb, T, w[f] * 0.25f, out, nwords,
                 false);
}

// fused combine3 (9-table mode): out = sum_f (w[f]/4)*(emb_f + (A+B+C)/64)
__global__ void combine3_kernel(const float* __restrict__ e0, const float* __restrict__ e1,
                                const float* __restrict__ e2, const unsigned* __restrict__ t0,
                                const unsigned* __restrict__ t1, const unsigned* __restrict__ t2,
                                const float* __restrict__ w, float* __restrict__ out,
                                int nwords) {
    int i = blockIdx.x * blockDim.x + threadIdx.x;
    if (i >= nwords) return;
    const float kInv = 1.f / 64.f;
    float c0 = w[0] * 0.25f, c1 = w[1] * 0.25f, c2 = w[2] * 0.25f;
    int r = i >> 4, wd = i & 15;
    size_t base = ((size_t)r << 6) + wd;
    float4 s0 = dec_sum3(t0, i, nwords);
    float4 s1 = dec_sum3(t1, i, nwords);
    float4 s2 = dec_sum3(t2, i, nwords);
    out[base]      = c0 * (e0[base]      + kInv * s0.x) + c1 * (e1[base]      + kInv * s1.x)
                   + c2 * (e2[base]      + kInv * s2.x);
    out[base + 16] = c0 * (e0[base + 16] + kInv * s0.y) + c1 * (e1[base + 16] + kInv * s1.y)
                   + c2 * (e2[base + 16] + kInv * s2.y);
    out[base + 32] = c0 * (e0[base + 32] + kInv * s0.z) + c1 * (e1[base + 32] + kInv * s1.z)
                   + c2 * (e2[base + 32] + kInv * s2.z);
    out[base + 48] = c0 * (e0[base + 48] + kInv * s0.w) + c1 * (e1[base + 48] + kInv * s1.w)
                   + c2 * (e2[base + 48] + kInv * s2.w);
}

// ---- register-accumulator pull SpMM (round-13/14 proven, 75us). One wave per
// row; eighth-wave (8 lanes x uint2 = 8 fp8 dims) per edge; 8 edges concurrent
// x 2-deep pipeline. Writes ONLY the fp8 y-table. Layout-agnostic. ----
__global__ void spmm_reg_kernel(const int* __restrict__ rlo, const int* __restrict__ rhi,
                                const unsigned* __restrict__ cs, const uint2* __restrict__ x2,
                                uint2* __restrict__ y2, int nrows) {
    int gid = blockIdx.x * blockDim.x + threadIdx.x;
    int row = gid >> 6;
    int lane = gid & 63;
    if (row >= nrows) return;
    int s = rlo[row], e = rhi[row];
    int q = lane >> 3, sub = lane & 7;
    float ac[8], bc[8];
    #pragma unroll
    for (int d = 0; d < 8; ++d) { ac[d] = 0.f; bc[d] = 0.f; }
    int k = s + q;
    for (; k + 8 < e; k += 16) {
        unsigned ed0 = cs[k], ed1 = cs[k + 8];
        uint2 g0 = x2[((size_t)(ed0 >> 14) << 3) + sub];
        uint2 g1 = x2[((size_t)(ed1 >> 14) << 3) + sub];
        float v0 = __uint_as_float((ed0 & 0x3FFFu) << 18);
        float v1 = __uint_as_float((ed1 & 0x3FFFu) << 18);
        v2f l0 = __builtin_amdgcn_cvt_pk_f32_fp8((int)g0.x, false);
        v2f h0 = __builtin_amdgcn_cvt_pk_f32_fp8((int)g0.x, true);
        v2f l1 = __builtin_amdgcn_cvt_pk_f32_fp8((int)g0.y, false);
        v2f h1 = __builtin_amdgcn_cvt_pk_f32_fp8((int)g0.y, true);
        ac[0] += v0 * l0.x; ac[1] += v0 * l0.y; ac[2] += v0 * h0.x; ac[3] += v0 * h0.y;
        ac[4] += v0 * l1.x; ac[5] += v0 * l1.y; ac[6] += v0 * h1.x; ac[7] += v0 * h1.y;
        v2f l2 = __builtin_amdgcn_cvt_pk_f32_fp8((int)g1.x, false);
        v2f h2 = __builtin_amdgcn_cvt_pk_f32_fp8((int)g1.x, true);
        v2f l3 = __builtin_amdgcn_cvt_pk_f32_fp8((int)g1.y, false);
        v2f h3 = __builtin_amdgcn_cvt_pk_f32_fp8((int)g1.y, true);
        bc[0] += v1 * l2.x; bc[1] += v1 * l2.y; bc[2] += v1 * h2.x; bc[3] += v1 * h2.y;
        bc[4] += v1 * l3.x; bc[5] += v1 * l3.y; bc[6] += v1 * h3.x; bc[7] += v1 * h3.y;
    }
    for (; k < e; k += 8) {
        unsigned ed = cs[k];
        uint2 g = x2[((size_t)(ed >> 14) << 3) + sub];
        float vv = __uint_as_float((ed & 0x3FFFu) << 18);
        v2f l0 = __builtin_amdgcn_cvt_pk_f32_fp8((int)g.x, false);
        v2f h0 = __builtin_amdgcn_cvt_pk_f32_fp8((int)g.x, true);
        v2f l1 = __builtin_amdgcn_cvt_pk_f32_fp8((int)g.y, false);
        v2f h1 = __builtin_amdgcn_cvt_pk_f32_fp8((int)g.y, true);
        ac[0] += vv * l0.x; ac[1] += vv * l0.y; ac[2] += vv * h0.x; ac[3] += vv * h0.y;
        ac[4] += vv * l1.x; ac[5] += vv * l1.y; ac[6] += vv * h1.x; ac[7] += vv * h1.y;
    }
    #pragma unroll
    for (int d = 0; d < 8; ++d) {
        float a = ac[d] + bc[d];
        a += __shfl_xor(a, 8);
        a += __shfl_xor(a, 16);
        a += __shfl_xor(a, 32);
        ac[d] = a;
    }
    if (q == 0) {
        int p0 = __builtin_amdgcn_cvt_pk_fp8_f32(ac[0], ac[1], 0, false);
        p0 = __builtin_amdgcn_cvt_pk_fp8_f32(ac[2], ac[3], p0, true);
        int p1 = __builtin_amdgcn_cvt_pk_fp8_f32(ac[4], ac[5], 0, false);
        p1 = __builtin_amdgcn_cvt_pk_fp8_f32(ac[6], ac[7], p1, true);
        uint2 o;
        o.x = (unsigned)p0;
        o.y = (unsigned)p1;
        y2[((size_t)row << 3) + sub] = o;
    }
}

extern "C" void kernel_launch(void* const* d_in, const int* in_sizes, int n_in,
                              void* d_out, int out_size, void* d_ws, size_t ws_size,
                              hipStream_t stream) {
    const float* emb[3]  = {(const float*)d_in[0], (const float*)d_in[1], (const float*)d_in[2]};
    const int*   gidx[3] = {(const int*)d_in[3],   (const int*)d_in[5],   (const int*)d_in[7]};
    const float* gval[3] = {(const float*)d_in[4], (const float*)d_in[6], (const float*)d_in[8]};
    const float* w = (const float*)d_in[9];
    float* out = (float*)d_out;

    const int nnz = in_sizes[4];
    const size_t bufElems = (size_t)N_TOTAL * DIM;       // 9.6M
    const int nwords = (int)(bufElems / 4);              // 2.4M words per fp8 table
    const size_t fp8Bytes = (size_t)nwords * 4;          // 9.6 MB
    const size_t capElems = (size_t)NBUCK * CAP;         // 5.31M entries

    // ws layout (single-mode base, 63.9MB + tables):
    //   bcs 21.2 | brl 10.6 | cs2 21.2 | emb8 9.6 | rlo/rhi/bcur ~1.2 | tables
    char* base = (char*)d_ws;
    unsigned*       bcs  = (unsigned*)base;
    unsigned short* brl  = (unsigned short*)(base + capElems * 4);
    unsigned*       cs2  = (unsigned*)(base + capElems * 6);
    unsigned*       emb8 = (unsigned*)(base + capElems * 10);
    int*            rlo  = (int*)(base + capElems * 10 + fp8Bytes);
    int*            rhi  = rlo + N_TOTAL;
    int*            bcur = rhi + N_TOTAL;
    char*           tab  = (char*)(bcur + NBUCK + 64);
    const size_t needFused = (size_t)(tab - base) + (size_t)9 * fp8Bytes;  // ~150.3 MB
    const bool fused = ws_size >= needFused;

    const int nCvt = (nwords + 255) / 256;               // 9375
    dim3 binGrid((nnz + CHUNK - 1) / CHUNK);             // 1172
    dim3 rowGrid((unsigned)(((size_t)N_TOTAL * 64 + 255) / 256));
    dim3 cmbGrid((nwords + 255) / 256);

    fill_bcur_kernel<<<2, 256, 0, stream>>>(bcur);

    for (int f = 0; f < 3; ++f) {
        unsigned* tabF = (unsigned*)(tab + (size_t)(fused ? 3 * f : 0) * fp8Bytes);
        unsigned* A8 = tabF;
        unsigned* B8 = tabF + nwords;
        unsigned* C8 = tabF + 2 * (size_t)nwords;

        bin_kernel<<<binGrid, 256, 0, stream>>>(gidx[f], gval[f], bcur, bcs, brl, nnz);

        // merged: scatterc(f) + conv(f) [+ combine(f-1) in 3-table mode]
        int hasCmb = (!fused && f > 0) ? 1 : 0;
        const unsigned* Tprev = (const unsigned*)tab;    // 3-table mode: prev tables
        const float* embPrev = (f > 0) ? emb[f - 1] : emb[0];
        dim3 scvGrid(NBUCK + nCvt + (hasCmb ? nCvt : 0));
        scv_kernel<<<scvGrid, 256, 0, stream>>>(bcs, brl, bcur, rlo, rhi, cs2,
                                                emb[f], emb8, embPrev, Tprev,
                                                w, f - 1, out, nwords, nCvt);

        // 3 propagation layers
        spmm_reg_kernel<<<rowGrid, 256, 0, stream>>>(rlo, rhi, cs2, (const uint2*)emb8,
                                                     (uint2*)A8, N_TOTAL);
        spmm_reg_kernel<<<rowGrid, 256, 0, stream>>>(rlo, rhi, cs2, (const uint2*)A8,
                                                     (uint2*)B8, N_TOTAL);
        spmm_reg_kernel<<<rowGrid, 256, 0, stream>>>(rlo, rhi, cs2, (const uint2*)B8,
                                                     (uint2*)C8, N_TOTAL);
    }

    if (fused) {
        const unsigned* t0 = (const unsigned*)tab;
        const unsigned* t1 = t0 + 3 * (size_t)nwords;
        const unsigned* t2 = t0 + 6 * (size_t)nwords;
        combine3_kernel<<<cmbGrid, 256, 0, stream>>>(emb[0], emb[1], emb[2], t0, t1, t2,
                                                     w, out, nwords);
    } else {
        // last factor's combine (factors 0/1 were folded inside scv of f+1)
        combine_kernel<<<cmbGrid, 256, 0, stream>>>(emb[2], (const unsigned*)tab, w, 2,
                                                    out, nwords);
    }
}

// Round 17
// 971.530 us; speedup vs baseline: 5.6365x; 1.1042x over previous
//
#include <hip/hip_runtime.h>

#define N_TOTAL 150000   // N_USERS + M_ITEMS
#define DIM 64
#define RPB 293          // rows per bucket
#define NBUCK 512        // buckets
#define MAGIC 14658592u  // ceil(2^32/293): __umulhi(r,MAGIC) == r/293 for r<2^24
#define CAP 10368        // fixed bucket capacity (mean 9375 + ~10 sigma)
#define CHUNK 8192       // edges per binning block (512 thr x 16) -- round-14 proven

typedef float v2f __attribute__((ext_vector_type(2)));

__global__ void fill_bcur_kernel(int* __restrict__ bcur) {
    int t = blockIdx.x * 256 + threadIdx.x;
    if (t < NBUCK) bcur[t] = t * CAP;
}

// Phase B (round-14 proven): LDS-sorted multisplit into 512 row-range buckets;
// coalesced stream-out. Records: bcs[dst] = col(18b)<<14 | val14 ; brl = rowLocal.
__global__ void bin_kernel(const int* __restrict__ idx, const float* __restrict__ val,
                           int* __restrict__ bcur, unsigned* __restrict__ bcs,
                           unsigned short* __restrict__ brl, int nnz) {
    __shared__ unsigned scs[CHUNK];       // 32 KB
    __shared__ unsigned srow[CHUNK];      // 32 KB
    __shared__ int lcnt[NBUCK];
    __shared__ int lstart[NBUCK + 1];
    __shared__ int gbase[NBUCK];
    int t = threadIdx.x;
    int base = blockIdx.x * CHUNK;
    int nEdges = min(CHUNK, nnz - base);
    lcnt[t] = 0;
    __syncthreads();
    unsigned mycs[16];
    int myrow[16], myb[16];
    #pragma unroll
    for (int i = 0; i < 16; ++i) {
        int e = base + t + i * 512;
        if (e < nnz) {
            int r = idx[e];
            int b = (int)__umulhi((unsigned)r, MAGIC);
            myb[i] = b;
            myrow[i] = r;
            unsigned v14 = (__float_as_uint(val[e]) + 0x20000u) >> 18;
            mycs[i] = ((unsigned)idx[nnz + e] << 14) | v14;
            atomicAdd(&lcnt[b], 1);
        } else {
            myb[i] = -1;
        }
    }
    __syncthreads();
    int c = lcnt[t];
    lstart[t] = c;
    __syncthreads();
    for (int off = 1; off < 512; off <<= 1) {
        int x = (t >= off) ? lstart[t - off] : 0;
        __syncthreads();
        lstart[t] += x;
        __syncthreads();
    }
    int incl = lstart[t];
    __syncthreads();
    lstart[t] = incl - c;                  // exclusive
    if (t == 511) lstart[512] = incl;      // total
    gbase[t] = c ? atomicAdd(&bcur[t], c) : 0;
    lcnt[t] = 0;                           // reuse as placement cursor
    __syncthreads();
    #pragma unroll
    for (int i = 0; i < 16; ++i) {
        int b = myb[i];
        if (b >= 0) {
            int o = atomicAdd(&lcnt[b], 1);
            int p = lstart[b] + o;
            scs[p] = mycs[i];
            srow[p] = (unsigned)myrow[i];
        }
    }
    __syncthreads();
    for (int p = t; p < nEdges; p += 512) {
        int r = (int)srow[p];
        int b = (int)__umulhi((unsigned)r, MAGIC);
        int dst = gbase[b] + (p - lstart[b]);
        if (dst < (b + 1) * CAP) {         // overflow guard (never hit)
            bcs[dst] = scs[p];
            brl[dst] = (unsigned short)(r - b * RPB);
        }
    }
}

// ---- device bodies for the merged scatterc+conv+combine dispatch ----

// Per-bucket ROW-grouped CSR placement; resets bcur[b] for the next factor.
__device__ void scatterc_body(int b, const unsigned* __restrict__ bcs,
                              const unsigned short* __restrict__ brl,
                              int* __restrict__ bcur,
                              int* __restrict__ rlo, int* __restrict__ rhi,
                              unsigned* __restrict__ cs2) {
    __shared__ int hist[RPB];
    __shared__ int ssc[256];
    int t = threadIdx.x;
    int s = b * CAP, e = min(bcur[b], s + CAP);
    for (int i = t; i < RPB; i += 256) hist[i] = 0;
    __syncthreads();
    for (int k = s + t; k < e; k += 256)
        atomicAdd(&hist[brl[k]], 1);
    __syncthreads();
    int i0 = 2 * t;
    int c0 = (i0 < RPB) ? hist[i0] : 0;
    int c1 = (i0 + 1 < RPB) ? hist[i0 + 1] : 0;
    int s2 = c0 + c1;
    ssc[t] = s2;
    __syncthreads();
    for (int off = 1; off < 256; off <<= 1) {
        int x = (t >= off) ? ssc[t - off] : 0;
        __syncthreads();
        ssc[t] += x;
        __syncthreads();
    }
    int excl = ssc[t] - s2;
    __syncthreads();
    int base0 = s + excl, base1 = s + excl + c0;
    if (i0 < RPB) {
        int row = b * RPB + i0;
        if (row < N_TOTAL) { rlo[row] = base0; rhi[row] = base0 + c0; }
        hist[i0] = base0;
    }
    if (i0 + 1 < RPB) {
        int row = b * RPB + i0 + 1;
        if (row < N_TOTAL) { rlo[row] = base1; rhi[row] = base1 + c1; }
        hist[i0 + 1] = base1;
    }
    __syncthreads();
    for (int k = s + t; k < e; k += 256) {
        int rl_ = brl[k];
        int o = atomicAdd(&hist[rl_], 1);
        cs2[o] = bcs[k];
    }
    __syncthreads();
    if (t == 0) bcur[b] = s;              // reset cursor for next factor's bin
}

// f32 -> fp8(e4m3, x64) DIM-PERMUTED table: word w of a row packs dims
// {w, w+16, w+32, w+48}.
__device__ void conv_body(int i, const float* __restrict__ x, unsigned* __restrict__ y,
                          int nwords) {
    if (i >= nwords) return;
    int row = i >> 4, w_ = i & 15;
    const float* xr = x + ((size_t)row << 6) + w_;
    int p = __builtin_amdgcn_cvt_pk_fp8_f32(xr[0] * 64.f, xr[16] * 64.f, 0, false);
    p = __builtin_amdgcn_cvt_pk_fp8_f32(xr[32] * 64.f, xr[48] * 64.f, p, true);
    y[i] = (unsigned)p;
}

// decode permuted word i of 3 stacked tables (A at 0, B at nwords, C at 2*nwords)
__device__ inline float4 dec_sum3(const unsigned* __restrict__ T, int i, int nwords) {
    unsigned a = T[i], b = T[i + nwords], c = T[i + 2 * nwords];
    v2f alo = __builtin_amdgcn_cvt_pk_f32_fp8((int)a, false);
    v2f ahi = __builtin_amdgcn_cvt_pk_f32_fp8((int)a, true);
    v2f blo = __builtin_amdgcn_cvt_pk_f32_fp8((int)b, false);
    v2f bhi = __builtin_amdgcn_cvt_pk_f32_fp8((int)b, true);
    v2f clo = __builtin_amdgcn_cvt_pk_f32_fp8((int)c, false);
    v2f chi = __builtin_amdgcn_cvt_pk_f32_fp8((int)c, true);
    float4 r;
    r.x = alo.x + blo.x + clo.x;
    r.y = alo.y + blo.y + clo.y;
    r.z = ahi.x + bhi.x + chi.x;
    r.w = ahi.y + bhi.y + chi.y;
    return r;
}

// out (+)= c * (emb + (A+B+C)/64), permuted-table decode
__device__ void combine_body(int i, const float* __restrict__ emb,
                             const unsigned* __restrict__ T, float c,
                             float* __restrict__ out, int nwords, bool first) {
    if (i >= nwords) return;
    const float kInv = 1.f / 64.f;
    int r = i >> 4, wd = i & 15;
    size_t base = ((size_t)r << 6) + wd;
    float4 s = dec_sum3(T, i, nwords);
    float v0 = c * (emb[base] + kInv * s.x);
    float v1 = c * (emb[base + 16] + kInv * s.y);
    float v2 = c * (emb[base + 32] + kInv * s.z);
    float v3 = c * (emb[base + 48] + kInv * s.w);
    if (first) {
        out[base] = v0; out[base + 16] = v1; out[base + 32] = v2; out[base + 48] = v3;
    } else {
        out[base] += v0; out[base + 16] += v1; out[base + 32] += v2; out[base + 48] += v3;
    }
}

// Merged dispatch: blocks [0,NBUCK) scatterc(f); [NBUCK,NBUCK+nCvt) conv(f);
// rest (if present) combine(f-1). All independent buffers.
__global__ void scv_kernel(const unsigned* __restrict__ bcs,
                           const unsigned short* __restrict__ brl,
                           int* __restrict__ bcur, int* __restrict__ rlo,
                           int* __restrict__ rhi, unsigned* __restrict__ cs2,
                           const float* __restrict__ embf, unsigned* __restrict__ emb8,
                           const float* __restrict__ embp, const unsigned* __restrict__ Tp,
                           const float* __restrict__ w, int fprev, float* __restrict__ out,
                           int nwords, int nCvt) {
    int b = blockIdx.x;
    if (b < NBUCK) {
        scatterc_body(b, bcs, brl, bcur, rlo, rhi, cs2);
        return;
    }
    b -= NBUCK;
    if (b < nCvt) {
        conv_body(b * 256 + (int)threadIdx.x, embf, emb8, nwords);
        return;
    }
    b -= nCvt;
    combine_body(b * 256 + (int)threadIdx.x, embp, Tp, w[fprev] * 0.25f, out, nwords,
                 fprev == 0);
}

// standalone combine (last factor, 3-table mode)
__global__ void combine_kernel(const float* __restrict__ emb, const unsigned* __restrict__ T,
                               const float* __restrict__ w, int f, float* __restrict__ out,
                               int nwords) {
    combine_body(blockIdx.x * 256 + (int)threadIdx.x, emb, T, w[f] * 0.25f, out, nwords,
                 false);
}

// fused combine3 (9-table mode): out = sum_f (w[f]/4)*(emb_f + (A+B+C)/64)
__global__ void combine3_kernel(const float* __restrict__ e0, const float* __restrict__ e1,
                                const float* __restrict__ e2, const unsigned* __restrict__ t0,
                                const unsigned* __restrict__ t1, const unsigned* __restrict__ t2,
                                const float* __restrict__ w, float* __restrict__ out,
                                int nwords) {
    int i = blockIdx.x * blockDim.x + threadIdx.x;
    if (i >= nwords) return;
    const float kInv = 1.f / 64.f;
    float c0 = w[0] * 0.25f, c1 = w[1] * 0.25f, c2 = w[2] * 0.25f;
    int r = i >> 4, wd = i & 15;
    size_t base = ((size_t)r << 6) + wd;
    float4 s0 = dec_sum3(t0, i, nwords);
    float4 s1 = dec_sum3(t1, i, nwords);
    float4 s2 = dec_sum3(t2, i, nwords);
    out[base]      = c0 * (e0[base]      + kInv * s0.x) + c1 * (e1[base]      + kInv * s1.x)
                   + c2 * (e2[base]      + kInv * s2.x);
    out[base + 16] = c0 * (e0[base + 16] + kInv * s0.y) + c1 * (e1[base + 16] + kInv * s1.y)
                   + c2 * (e2[base + 16] + kInv * s2.y);
    out[base + 32] = c0 * (e0[base + 32] + kInv * s0.z) + c1 * (e1[base + 32] + kInv * s1.z)
                   + c2 * (e2[base + 32] + kInv * s2.z);
    out[base + 48] = c0 * (e0[base + 48] + kInv * s0.w) + c1 * (e1[base + 48] + kInv * s1.w)
                   + c2 * (e2[base + 48] + kInv * s2.w);
}

// ---- register-accumulator pull SpMM (round-13/14 proven, 75us). One wave per
// row; eighth-wave (8 lanes x uint2 = 8 fp8 dims) per edge; 8 edges concurrent
// x 2-deep pipeline. Writes ONLY the fp8 y-table. Layout-agnostic. ----
__global__ void spmm_reg_kernel(const int* __restrict__ rlo, const int* __restrict__ rhi,
                                const unsigned* __restrict__ cs, const uint2* __restrict__ x2,
                                uint2* __restrict__ y2, int nrows) {
    int gid = blockIdx.x * blockDim.x + threadIdx.x;
    int row = gid >> 6;
    int lane = gid & 63;
    if (row >= nrows) return;
    int s = rlo[row], e = rhi[row];
    int q = lane >> 3, sub = lane & 7;
    float ac[8], bc[8];
    #pragma unroll
    for (int d = 0; d < 8; ++d) { ac[d] = 0.f; bc[d] = 0.f; }
    int k = s + q;
    for (; k + 8 < e; k += 16) {
        unsigned ed0 = cs[k], ed1 = cs[k + 8];
        uint2 g0 = x2[((size_t)(ed0 >> 14) << 3) + sub];
        uint2 g1 = x2[((size_t)(ed1 >> 14) << 3) + sub];
        float v0 = __uint_as_float((ed0 & 0x3FFFu) << 18);
        float v1 = __uint_as_float((ed1 & 0x3FFFu) << 18);
        v2f l0 = __builtin_amdgcn_cvt_pk_f32_fp8((int)g0.x, false);
        v2f h0 = __builtin_amdgcn_cvt_pk_f32_fp8((int)g0.x, true);
        v2f l1 = __builtin_amdgcn_cvt_pk_f32_fp8((int)g0.y, false);
        v2f h1 = __builtin_amdgcn_cvt_pk_f32_fp8((int)g0.y, true);
        ac[0] += v0 * l0.x; ac[1] += v0 * l0.y; ac[2] += v0 * h0.x; ac[3] += v0 * h0.y;
        ac[4] += v0 * l1.x; ac[5] += v0 * l1.y; ac[6] += v0 * h1.x; ac[7] += v0 * h1.y;
        v2f l2 = __builtin_amdgcn_cvt_pk_f32_fp8((int)g1.x, false);
        v2f h2 = __builtin_amdgcn_cvt_pk_f32_fp8((int)g1.x, true);
        v2f l3 = __builtin_amdgcn_cvt_pk_f32_fp8((int)g1.y, false);
        v2f h3 = __builtin_amdgcn_cvt_pk_f32_fp8((int)g1.y, true);
        bc[0] += v1 * l2.x; bc[1] += v1 * l2.y; bc[2] += v1 * h2.x; bc[3] += v1 * h2.y;
        bc[4] += v1 * l3.x; bc[5] += v1 * l3.y; bc[6] += v1 * h3.x; bc[7] += v1 * h3.y;
    }
    for (; k < e; k += 8) {
        unsigned ed = cs[k];
        uint2 g = x2[((size_t)(ed >> 14) << 3) + sub];
        float vv = __uint_as_float((ed & 0x3FFFu) << 18);
        v2f l0 = __builtin_amdgcn_cvt_pk_f32_fp8((int)g.x, false);
        v2f h0 = __builtin_amdgcn_cvt_pk_f32_fp8((int)g.x, true);
        v2f l1 = __builtin_amdgcn_cvt_pk_f32_fp8((int)g.y, false);
        v2f h1 = __builtin_amdgcn_cvt_pk_f32_fp8((int)g.y, true);
        ac[0] += vv * l0.x; ac[1] += vv * l0.y; ac[2] += vv * h0.x; ac[3] += vv * h0.y;
        ac[4] += vv * l1.x; ac[5] += vv * l1.y; ac[6] += vv * h1.x; ac[7] += vv * h1.y;
    }
    #pragma unroll
    for (int d = 0; d < 8; ++d) {
        float a = ac[d] + bc[d];
        a += __shfl_xor(a, 8);
        a += __shfl_xor(a, 16);
        a += __shfl_xor(a, 32);
        ac[d] = a;
    }
    if (q == 0) {
        int p0 = __builtin_amdgcn_cvt_pk_fp8_f32(ac[0], ac[1], 0, false);
        p0 = __builtin_amdgcn_cvt_pk_fp8_f32(ac[2], ac[3], p0, true);
        int p1 = __builtin_amdgcn_cvt_pk_fp8_f32(ac[4], ac[5], 0, false);
        p1 = __builtin_amdgcn_cvt_pk_fp8_f32(ac[6], ac[7], p1, true);
        uint2 o;
        o.x = (unsigned)p0;
        o.y = (unsigned)p1;
        y2[((size_t)row << 3) + sub] = o;
    }
}

extern "C" void kernel_launch(void* const* d_in, const int* in_sizes, int n_in,
                              void* d_out, int out_size, void* d_ws, size_t ws_size,
                              hipStream_t stream) {
    const float* emb[3]  = {(const float*)d_in[0], (const float*)d_in[1], (const float*)d_in[2]};
    const int*   gidx[3] = {(const int*)d_in[3],   (const int*)d_in[5],   (const int*)d_in[7]};
    const float* gval[3] = {(const float*)d_in[4], (const float*)d_in[6], (const float*)d_in[8]};
    const float* w = (const float*)d_in[9];
    float* out = (float*)d_out;

    const int nnz = in_sizes[4];
    const size_t bufElems = (size_t)N_TOTAL * DIM;       // 9.6M
    const int nwords = (int)(bufElems / 4);              // 2.4M words per fp8 table
    const size_t fp8Bytes = (size_t)nwords * 4;          // 9.6 MB
    const size_t capElems = (size_t)NBUCK * CAP;         // 5.31M entries

    // ws layout: bcs 21.2 | brl 10.6 | cs2 21.2 | emb8 9.6 | rlo/rhi/bcur | tables
    char* base = (char*)d_ws;
    unsigned*       bcs  = (unsigned*)base;
    unsigned short* brl  = (unsigned short*)(base + capElems * 4);
    unsigned*       cs2  = (unsigned*)(base + capElems * 6);
    unsigned*       emb8 = (unsigned*)(base + capElems * 10);
    int*            rlo  = (int*)(base + capElems * 10 + fp8Bytes);
    int*            rhi  = rlo + N_TOTAL;
    int*            bcur = rhi + N_TOTAL;
    char*           tab  = (char*)(bcur + NBUCK + 64);
    const size_t needFused = (size_t)(tab - base) + (size_t)9 * fp8Bytes;  // ~150.3 MB
    const bool fused = ws_size >= needFused;

    const int nCvt = (nwords + 255) / 256;               // 9375
    dim3 binGrid((nnz + CHUNK - 1) / CHUNK);             // 586
    dim3 rowGrid((unsigned)(((size_t)N_TOTAL * 64 + 255) / 256));
    dim3 cmbGrid((nwords + 255) / 256);

    fill_bcur_kernel<<<2, 256, 0, stream>>>(bcur);

    for (int f = 0; f < 3; ++f) {
        unsigned* tabF = (unsigned*)(tab + (size_t)(fused ? 3 * f : 0) * fp8Bytes);
        unsigned* A8 = tabF;
        unsigned* B8 = tabF + nwords;
        unsigned* C8 = tabF + 2 * (size_t)nwords;

        bin_kernel<<<binGrid, 512, 0, stream>>>(gidx[f], gval[f], bcur, bcs, brl, nnz);

        // merged: scatterc(f) + conv(f) [+ combine(f-1) in 3-table mode]
        int hasCmb = (!fused && f > 0) ? 1 : 0;
        const unsigned* Tprev = (const unsigned*)tab;    // 3-table mode: prev tables
        const float* embPrev = (f > 0) ? emb[f - 1] : emb[0];
        dim3 scvGrid(NBUCK + nCvt + (hasCmb ? nCvt : 0));
        scv_kernel<<<scvGrid, 256, 0, stream>>>(bcs, brl, bcur, rlo, rhi, cs2,
                                                emb[f], emb8, embPrev, Tprev,
                                                w, f - 1, out, nwords, nCvt);

        // 3 propagation layers
        spmm_reg_kernel<<<rowGrid, 256, 0, stream>>>(rlo, rhi, cs2, (const uint2*)emb8,
                                                     (uint2*)A8, N_TOTAL);
        spmm_reg_kernel<<<rowGrid, 256, 0, stream>>>(rlo, rhi, cs2, (const uint2*)A8,
                                                     (uint2*)B8, N_TOTAL);
        spmm_reg_kernel<<<rowGrid, 256, 0, stream>>>(rlo, rhi, cs2, (const uint2*)B8,
                                                     (uint2*)C8, N_TOTAL);
    }

    if (fused) {
        const unsigned* t0 = (const unsigned*)tab;
        const unsigned* t1 = t0 + 3 * (size_t)nwords;
        const unsigned* t2 = t0 + 6 * (size_t)nwords;
        combine3_kernel<<<cmbGrid, 256, 0, stream>>>(emb[0], emb[1], emb[2], t0, t1, t2,
                                                     w, out, nwords);
    } else {
        // last factor's combine (factors 0/1 were folded inside scv of f+1)
        combine_kernel<<<cmbGrid, 256, 0, stream>>>(emb[2], (const unsigned*)tab, w, 2,
                                                    out, nwords);
    }
}

// Round 18
// 965.578 us; speedup vs baseline: 5.6713x; 1.0062x over previous
//
#include <hip/hip_runtime.h>

#define N_TOTAL 150000   // N_USERS + M_ITEMS
#define DIM 64
#define RPB 293          // rows per bucket
#define NBUCK 512        // buckets
#define MAGIC 14658592u  // ceil(2^32/293): __umulhi(r,MAGIC) == r/293 for r<2^24
#define CAP 10368        // fixed bucket capacity (mean 9375 + ~10 sigma)
#define CHUNK 8192       // edges per binning block (512 thr x 16) -- proven

typedef float v2f __attribute__((ext_vector_type(2)));

__global__ void fill_bcur_kernel(int* __restrict__ bcur) {
    int t = blockIdx.x * 256 + threadIdx.x;
    if (t < NBUCK) bcur[t] = t * CAP;
}

// Phase B: LDS-sorted multisplit into 512 row-range buckets; coalesced stream-out.
// Records: bcs[dst] = val14(top 14b, f32-aligned) | col(18b low) ; brl = rowLocal.
// Scan: per-wave shfl inclusive scan + 8-entry serial combine (3 barriers).
__global__ void bin_kernel(const int* __restrict__ idx, const float* __restrict__ val,
                           int* __restrict__ bcur, unsigned* __restrict__ bcs,
                           unsigned short* __restrict__ brl, int nnz) {
    __shared__ unsigned scs[CHUNK];       // 32 KB
    __shared__ unsigned srow[CHUNK];      // 32 KB
    __shared__ int lcnt[NBUCK];
    __shared__ int lstart[NBUCK];
    __shared__ int gbase[NBUCK];
    __shared__ int wsum[8];
    int t = threadIdx.x;
    int base = blockIdx.x * CHUNK;
    int nEdges = min(CHUNK, nnz - base);
    lcnt[t] = 0;
    __syncthreads();
    unsigned mycs[16];
    int myrow[16], myb[16];
    #pragma unroll
    for (int i = 0; i < 16; ++i) {
        int e = base + t + i * 512;
        if (e < nnz) {
            int r = idx[e];
            int b = (int)__umulhi((unsigned)r, MAGIC);
            myb[i] = b;
            myrow[i] = r;
            unsigned vbits = (__float_as_uint(val[e]) + 0x20000u) & 0xFFFC0000u;
            mycs[i] = vbits | (unsigned)idx[nnz + e];
            atomicAdd(&lcnt[b], 1);
        } else {
            myb[i] = -1;
        }
    }
    __syncthreads();
    int c = lcnt[t];
    int lane = t & 63, wid = t >> 6;
    int incl = c;
    #pragma unroll
    for (int d = 1; d < 64; d <<= 1) {
        int y = __shfl_up(incl, d, 64);
        if (lane >= d) incl += y;
    }
    if (lane == 63) wsum[wid] = incl;
    __syncthreads();
    if (t == 0) {
        int s0 = 0;
        #pragma unroll
        for (int i = 0; i < 8; ++i) { int tmp = wsum[i]; wsum[i] = s0; s0 += tmp; }
    }
    __syncthreads();
    int excl = incl - c + wsum[wid];
    lstart[t] = excl;
    gbase[t] = c ? atomicAdd(&bcur[t], c) : 0;
    lcnt[t] = 0;                           // reuse as placement cursor
    __syncthreads();
    #pragma unroll
    for (int i = 0; i < 16; ++i) {
        int b = myb[i];
        if (b >= 0) {
            int o = atomicAdd(&lcnt[b], 1);
            int p = lstart[b] + o;
            scs[p] = mycs[i];
            srow[p] = (unsigned)myrow[i];
        }
    }
    __syncthreads();
    for (int p = t; p < nEdges; p += 512) {
        int r = (int)srow[p];
        int b = (int)__umulhi((unsigned)r, MAGIC);
        int dst = gbase[b] + (p - lstart[b]);
        if (dst < (b + 1) * CAP) {         // overflow guard (never hit)
            bcs[dst] = scs[p];
            brl[dst] = (unsigned short)(r - b * RPB);
        }
    }
}

// ---- device bodies for the merged scatterc+conv+combine dispatch ----

// Per-bucket ROW-grouped CSR placement; resets bcur[b] for the next factor.
__device__ void scatterc_body(int b, const unsigned* __restrict__ bcs,
                              const unsigned short* __restrict__ brl,
                              int* __restrict__ bcur,
                              int* __restrict__ rlo, int* __restrict__ rhi,
                              unsigned* __restrict__ cs2) {
    __shared__ int hist[RPB];
    __shared__ int ssc[256];
    int t = threadIdx.x;
    int s = b * CAP, e = min(bcur[b], s + CAP);
    for (int i = t; i < RPB; i += 256) hist[i] = 0;
    __syncthreads();
    for (int k = s + t; k < e; k += 256)
        atomicAdd(&hist[brl[k]], 1);
    __syncthreads();
    int i0 = 2 * t;
    int c0 = (i0 < RPB) ? hist[i0] : 0;
    int c1 = (i0 + 1 < RPB) ? hist[i0 + 1] : 0;
    int s2 = c0 + c1;
    ssc[t] = s2;
    __syncthreads();
    for (int off = 1; off < 256; off <<= 1) {
        int x = (t >= off) ? ssc[t - off] : 0;
        __syncthreads();
        ssc[t] += x;
        __syncthreads();
    }
    int excl = ssc[t] - s2;
    __syncthreads();
    int base0 = s + excl, base1 = s + excl + c0;
    if (i0 < RPB) {
        int row = b * RPB + i0;
        if (row < N_TOTAL) { rlo[row] = base0; rhi[row] = base0 + c0; }
        hist[i0] = base0;
    }
    if (i0 + 1 < RPB) {
        int row = b * RPB + i0 + 1;
        if (row < N_TOTAL) { rlo[row] = base1; rhi[row] = base1 + c1; }
        hist[i0 + 1] = base1;
    }
    __syncthreads();
    for (int k = s + t; k < e; k += 256) {
        int rl_ = brl[k];
        int o = atomicAdd(&hist[rl_], 1);
        cs2[o] = bcs[k];
    }
    __syncthreads();
    if (t == 0) bcur[b] = s;              // reset cursor for next factor's bin
}

// f32 -> fp8(e4m3, x64) DIM-PERMUTED table: word w of a row packs dims
// {w, w+16, w+32, w+48}.
__device__ void conv_body(int i, const float* __restrict__ x, unsigned* __restrict__ y,
                          int nwords) {
    if (i >= nwords) return;
    int row = i >> 4, w_ = i & 15;
    const float* xr = x + ((size_t)row << 6) + w_;
    int p = __builtin_amdgcn_cvt_pk_fp8_f32(xr[0] * 64.f, xr[16] * 64.f, 0, false);
    p = __builtin_amdgcn_cvt_pk_fp8_f32(xr[32] * 64.f, xr[48] * 64.f, p, true);
    y[i] = (unsigned)p;
}

// decode permuted word i of 3 stacked tables (A at 0, B at nwords, C at 2*nwords)
__device__ inline float4 dec_sum3(const unsigned* __restrict__ T, int i, int nwords) {
    unsigned a = T[i], b = T[i + nwords], c = T[i + 2 * nwords];
    v2f alo = __builtin_amdgcn_cvt_pk_f32_fp8((int)a, false);
    v2f ahi = __builtin_amdgcn_cvt_pk_f32_fp8((int)a, true);
    v2f blo = __builtin_amdgcn_cvt_pk_f32_fp8((int)b, false);
    v2f bhi = __builtin_amdgcn_cvt_pk_f32_fp8((int)b, true);
    v2f clo = __builtin_amdgcn_cvt_pk_f32_fp8((int)c, false);
    v2f chi = __builtin_amdgcn_cvt_pk_f32_fp8((int)c, true);
    float4 r;
    r.x = alo.x + blo.x + clo.x;
    r.y = alo.y + blo.y + clo.y;
    r.z = ahi.x + bhi.x + chi.x;
    r.w = ahi.y + bhi.y + chi.y;
    return r;
}

// out (+)= c * (emb + (A+B+C)/64), permuted-table decode
__device__ void combine_body(int i, const float* __restrict__ emb,
                             const unsigned* __restrict__ T, float c,
                             float* __restrict__ out, int nwords, bool first) {
    if (i >= nwords) return;
    const float kInv = 1.f / 64.f;
    int r = i >> 4, wd = i & 15;
    size_t base = ((size_t)r << 6) + wd;
    float4 s = dec_sum3(T, i, nwords);
    float v0 = c * (emb[base] + kInv * s.x);
    float v1 = c * (emb[base + 16] + kInv * s.y);
    float v2 = c * (emb[base + 32] + kInv * s.z);
    float v3 = c * (emb[base + 48] + kInv * s.w);
    if (first) {
        out[base] = v0; out[base + 16] = v1; out[base + 32] = v2; out[base + 48] = v3;
    } else {
        out[base] += v0; out[base + 16] += v1; out[base + 32] += v2; out[base + 48] += v3;
    }
}

// Merged dispatch: blocks [0,NBUCK) scatterc(f); [NBUCK,NBUCK+nCvt) conv(f);
// rest (if present) combine(f-1). All independent buffers.
__global__ void scv_kernel(const unsigned* __restrict__ bcs,
                           const unsigned short* __restrict__ brl,
                           int* __restrict__ bcur, int* __restrict__ rlo,
                           int* __restrict__ rhi, unsigned* __restrict__ cs2,
                           const float* __restrict__ embf, unsigned* __restrict__ emb8,
                           const float* __restrict__ embp, const unsigned* __restrict__ Tp,
                           const float* __restrict__ w, int fprev, float* __restrict__ out,
                           int nwords, int nCvt) {
    int b = blockIdx.x;
    if (b < NBUCK) {
        scatterc_body(b, bcs, brl, bcur, rlo, rhi, cs2);
        return;
    }
    b -= NBUCK;
    if (b < nCvt) {
        conv_body(b * 256 + (int)threadIdx.x, embf, emb8, nwords);
        return;
    }
    b -= nCvt;
    combine_body(b * 256 + (int)threadIdx.x, embp, Tp, w[fprev] * 0.25f, out, nwords,
                 fprev == 0);
}

// standalone combine (last factor, 3-table mode)
__global__ void combine_kernel(const float* __restrict__ emb, const unsigned* __restrict__ T,
                               const float* __restrict__ w, int f, float* __restrict__ out,
                               int nwords) {
    combine_body(blockIdx.x * 256 + (int)threadIdx.x, emb, T, w[f] * 0.25f, out, nwords,
                 false);
}

// fused combine3 (9-table mode): out = sum_f (w[f]/4)*(emb_f + (A+B+C)/64)
__global__ void combine3_kernel(const float* __restrict__ e0, const float* __restrict__ e1,
                                const float* __restrict__ e2, const unsigned* __restrict__ t0,
                                const unsigned* __restrict__ t1, const unsigned* __restrict__ t2,
                                const float* __restrict__ w, float* __restrict__ out,
                                int nwords) {
    int i = blockIdx.x * blockDim.x + threadIdx.x;
    if (i >= nwords) return;
    const float kInv = 1.f / 64.f;
    float c0 = w[0] * 0.25f, c1 = w[1] * 0.25f, c2 = w[2] * 0.25f;
    int r = i >> 4, wd = i & 15;
    size_t base = ((size_t)r << 6) + wd;
    float4 s0 = dec_sum3(t0, i, nwords);
    float4 s1 = dec_sum3(t1, i, nwords);
    float4 s2 = dec_sum3(t2, i, nwords);
    out[base]      = c0 * (e0[base]      + kInv * s0.x) + c1 * (e1[base]      + kInv * s1.x)
                   + c2 * (e2[base]      + kInv * s2.x);
    out[base + 16] = c0 * (e0[base + 16] + kInv * s0.y) + c1 * (e1[base + 16] + kInv * s1.y)
                   + c2 * (e2[base + 16] + kInv * s2.y);
    out[base + 32] = c0 * (e0[base + 32] + kInv * s0.z) + c1 * (e1[base + 32] + kInv * s1.z)
                   + c2 * (e2[base + 32] + kInv * s2.z);
    out[base + 48] = c0 * (e0[base + 48] + kInv * s0.w) + c1 * (e1[base + 48] + kInv * s1.w)
                   + c2 * (e2[base + 48] + kInv * s2.w);
}

// ---- register-accumulator pull SpMM. One wave per row; eighth-wave (8 lanes
// x uint2 = 8 fp8 dims) per edge; 8 edges concurrent x 2-deep pipeline.
// Packed v2f accumulators -> v_pk_fma_f32; cs decode = 2 ANDs. ----
__global__ void spmm_reg_kernel(const int* __restrict__ rlo, const int* __restrict__ rhi,
                                const unsigned* __restrict__ cs, const uint2* __restrict__ x2,
                                uint2* __restrict__ y2, int nrows) {
    int gid = blockIdx.x * blockDim.x + threadIdx.x;
    int row = gid >> 6;
    int lane = gid & 63;
    if (row >= nrows) return;
    int s = rlo[row], e = rhi[row];
    int q = lane >> 3, sub = lane & 7;
    v2f a0 = {0.f, 0.f}, a1 = {0.f, 0.f}, a2 = {0.f, 0.f}, a3 = {0.f, 0.f};
    v2f b0 = {0.f, 0.f}, b1 = {0.f, 0.f}, b2 = {0.f, 0.f}, b3 = {0.f, 0.f};
    int k = s + q;
    for (; k + 8 < e; k += 16) {
        unsigned ed0 = cs[k], ed1 = cs[k + 8];
        uint2 g0 = x2[((size_t)(ed0 & 0x3FFFFu) << 3) + sub];
        uint2 g1 = x2[((size_t)(ed1 & 0x3FFFFu) << 3) + sub];
        float v0 = __uint_as_float(ed0 & 0xFFFC0000u);
        float v1 = __uint_as_float(ed1 & 0xFFFC0000u);
        v2f vv0 = {v0, v0}, vv1 = {v1, v1};
        a0 += vv0 * __builtin_amdgcn_cvt_pk_f32_fp8((int)g0.x, false);
        a1 += vv0 * __builtin_amdgcn_cvt_pk_f32_fp8((int)g0.x, true);
        a2 += vv0 * __builtin_amdgcn_cvt_pk_f32_fp8((int)g0.y, false);
        a3 += vv0 * __builtin_amdgcn_cvt_pk_f32_fp8((int)g0.y, true);
        b0 += vv1 * __builtin_amdgcn_cvt_pk_f32_fp8((int)g1.x, false);
        b1 += vv1 * __builtin_amdgcn_cvt_pk_f32_fp8((int)g1.x, true);
        b2 += vv1 * __builtin_amdgcn_cvt_pk_f32_fp8((int)g1.y, false);
        b3 += vv1 * __builtin_amdgcn_cvt_pk_f32_fp8((int)g1.y, true);
    }
    for (; k < e; k += 8) {
        unsigned ed = cs[k];
        uint2 g = x2[((size_t)(ed & 0x3FFFFu) << 3) + sub];
        float vv = __uint_as_float(ed & 0xFFFC0000u);
        v2f vv2 = {vv, vv};
        a0 += vv2 * __builtin_amdgcn_cvt_pk_f32_fp8((int)g.x, false);
        a1 += vv2 * __builtin_amdgcn_cvt_pk_f32_fp8((int)g.x, true);
        a2 += vv2 * __builtin_amdgcn_cvt_pk_f32_fp8((int)g.y, false);
        a3 += vv2 * __builtin_amdgcn_cvt_pk_f32_fp8((int)g.y, true);
    }
    a0 += b0; a1 += b1; a2 += b2; a3 += b3;
    float r0 = a0.x, r1 = a0.y, r2 = a1.x, r3 = a1.y;
    float r4 = a2.x, r5 = a2.y, r6 = a3.x, r7 = a3.y;
    r0 += __shfl_xor(r0, 8); r0 += __shfl_xor(r0, 16); r0 += __shfl_xor(r0, 32);
    r1 += __shfl_xor(r1, 8); r1 += __shfl_xor(r1, 16); r1 += __shfl_xor(r1, 32);
    r2 += __shfl_xor(r2, 8); r2 += __shfl_xor(r2, 16); r2 += __shfl_xor(r2, 32);
    r3 += __shfl_xor(r3, 8); r3 += __shfl_xor(r3, 16); r3 += __shfl_xor(r3, 32);
    r4 += __shfl_xor(r4, 8); r4 += __shfl_xor(r4, 16); r4 += __shfl_xor(r4, 32);
    r5 += __shfl_xor(r5, 8); r5 += __shfl_xor(r5, 16); r5 += __shfl_xor(r5, 32);
    r6 += __shfl_xor(r6, 8); r6 += __shfl_xor(r6, 16); r6 += __shfl_xor(r6, 32);
    r7 += __shfl_xor(r7, 8); r7 += __shfl_xor(r7, 16); r7 += __shfl_xor(r7, 32);
    if (q == 0) {
        int p0 = __builtin_amdgcn_cvt_pk_fp8_f32(r0, r1, 0, false);
        p0 = __builtin_amdgcn_cvt_pk_fp8_f32(r2, r3, p0, true);
        int p1 = __builtin_amdgcn_cvt_pk_fp8_f32(r4, r5, 0, false);
        p1 = __builtin_amdgcn_cvt_pk_fp8_f32(r6, r7, p1, true);
        uint2 o;
        o.x = (unsigned)p0;
        o.y = (unsigned)p1;
        y2[((size_t)row << 3) + sub] = o;
    }
}

extern "C" void kernel_launch(void* const* d_in, const int* in_sizes, int n_in,
                              void* d_out, int out_size, void* d_ws, size_t ws_size,
                              hipStream_t stream) {
    const float* emb[3]  = {(const float*)d_in[0], (const float*)d_in[1], (const float*)d_in[2]};
    const int*   gidx[3] = {(const int*)d_in[3],   (const int*)d_in[5],   (const int*)d_in[7]};
    const float* gval[3] = {(const float*)d_in[4], (const float*)d_in[6], (const float*)d_in[8]};
    const float* w = (const float*)d_in[9];
    float* out = (float*)d_out;

    const int nnz = in_sizes[4];
    const size_t bufElems = (size_t)N_TOTAL * DIM;       // 9.6M
    const int nwords = (int)(bufElems / 4);              // 2.4M words per fp8 table
    const size_t fp8Bytes = (size_t)nwords * 4;          // 9.6 MB
    const size_t capElems = (size_t)NBUCK * CAP;         // 5.31M entries

    // ws layout: bcs 21.2 | brl 10.6 | cs2 21.2 | emb8 9.6 | rlo/rhi/bcur | tables
    char* base = (char*)d_ws;
    unsigned*       bcs  = (unsigned*)base;
    unsigned short* brl  = (unsigned short*)(base + capElems * 4);
    unsigned*       cs2  = (unsigned*)(base + capElems * 6);
    unsigned*       emb8 = (unsigned*)(base + capElems * 10);
    int*            rlo  = (int*)(base + capElems * 10 + fp8Bytes);
    int*            rhi  = rlo + N_TOTAL;
    int*            bcur = rhi + N_TOTAL;
    char*           tab  = (char*)(bcur + NBUCK + 64);
    const size_t needFused = (size_t)(tab - base) + (size_t)9 * fp8Bytes;  // ~150.3 MB
    const bool fused = ws_size >= needFused;

    const int nCvt = (nwords + 255) / 256;               // 9375
    dim3 binGrid((nnz + CHUNK - 1) / CHUNK);             // 586
    dim3 rowGrid((unsigned)(((size_t)N_TOTAL * 64 + 255) / 256));
    dim3 cmbGrid((nwords + 255) / 256);

    fill_bcur_kernel<<<2, 256, 0, stream>>>(bcur);

    for (int f = 0; f < 3; ++f) {
        unsigned* tabF = (unsigned*)(tab + (size_t)(fused ? 3 * f : 0) * fp8Bytes);
        unsigned* A8 = tabF;
        unsigned* B8 = tabF + nwords;
        unsigned* C8 = tabF + 2 * (size_t)nwords;

        bin_kernel<<<binGrid, 512, 0, stream>>>(gidx[f], gval[f], bcur, bcs, brl, nnz);

        // merged: scatterc(f) + conv(f) [+ combine(f-1) in 3-table mode]
        int hasCmb = (!fused && f > 0) ? 1 : 0;
        const unsigned* Tprev = (const unsigned*)tab;    // 3-table mode: prev tables
        const float* embPrev = (f > 0) ? emb[f - 1] : emb[0];
        dim3 scvGrid(NBUCK + nCvt + (hasCmb ? nCvt : 0));
        scv_kernel<<<scvGrid, 256, 0, stream>>>(bcs, brl, bcur, rlo, rhi, cs2,
                                                emb[f], emb8, embPrev, Tprev,
                                                w, f - 1, out, nwords, nCvt);

        // 3 propagation layers
        spmm_reg_kernel<<<rowGrid, 256, 0, stream>>>(rlo, rhi, cs2, (const uint2*)emb8,
                                                     (uint2*)A8, N_TOTAL);
        spmm_reg_kernel<<<rowGrid, 256, 0, stream>>>(rlo, rhi, cs2, (const uint2*)A8,
                                                     (uint2*)B8, N_TOTAL);
        spmm_reg_kernel<<<rowGrid, 256, 0, stream>>>(rlo, rhi, cs2, (const uint2*)B8,
                                                     (uint2*)C8, N_TOTAL);
    }

    if (fused) {
        const unsigned* t0 = (const unsigned*)tab;
        const unsigned* t1 = t0 + 3 * (size_t)nwords;
        const unsigned* t2 = t0 + 6 * (size_t)nwords;
        combine3_kernel<<<cmbGrid, 256, 0, stream>>>(emb[0], emb[1], emb[2], t0, t1, t2,
                                                     w, out, nwords);
    } else {
        // last factor's combine (factors 0/1 were folded inside scv of f+1)
        combine_kernel<<<cmbGrid, 256, 0, stream>>>(emb[2], (const unsigned*)tab, w, 2,
                                                    out, nwords);
    }
}